// Round 1
// baseline (465.035 us; speedup 1.0000x reference)
//
#include <hip/hip_runtime.h>
#include <hip/hip_bf16.h>

// PLIF forward: v += x_t; spike = (v - 1 > 0); v -= spike * 1.0
// x: [T=16, B*C*H*W], fp32. out: spikes, same shape/dtype.
// Memory-bound streaming recurrence; state v stays in registers.

#ifndef PLIF_T
#define PLIF_T 16
#endif

__global__ __launch_bounds__(256) void plif_fwd_kernel(
    const float4* __restrict__ x, float4* __restrict__ out, int n4) {
    int i = blockIdx.x * blockDim.x + threadIdx.x;
    if (i >= n4) return;

    float4 v = make_float4(0.f, 0.f, 0.f, 0.f);

    #pragma unroll
    for (int t = 0; t < PLIF_T; ++t) {
        const size_t off = (size_t)t * (size_t)n4 + (size_t)i;
        float4 xt = x[off];

        v.x += xt.x; v.y += xt.y; v.z += xt.z; v.w += xt.w;

        float sx = (v.x > 1.0f) ? 1.0f : 0.0f;
        float sy = (v.y > 1.0f) ? 1.0f : 0.0f;
        float sz = (v.z > 1.0f) ? 1.0f : 0.0f;
        float sw = (v.w > 1.0f) ? 1.0f : 0.0f;

        v.x -= sx; v.y -= sy; v.z -= sz; v.w -= sw;

        out[off] = make_float4(sx, sy, sz, sw);
    }
}

extern "C" void kernel_launch(void* const* d_in, const int* in_sizes, int n_in,
                              void* d_out, int out_size, void* d_ws, size_t ws_size,
                              hipStream_t stream) {
    const float* x = (const float*)d_in[0];
    float* out = (float*)d_out;

    const int total = in_sizes[0];          // T * B * C * H * W
    const int n = total / PLIF_T;           // spatial elements per timestep
    const int n4 = n / 4;                   // float4 groups per timestep

    const int block = 256;
    const int grid = (n4 + block - 1) / block;

    plif_fwd_kernel<<<grid, block, 0, stream>>>(
        (const float4*)x, (float4*)out, n4);
}

// Round 3
// 442.118 us; speedup vs baseline: 1.0518x; 1.0518x over previous
//
#include <hip/hip_runtime.h>
#include <hip/hip_bf16.h>

// PLIF forward: v += x_t; spike = (v - 1 > 0); v -= spike * 1.0
// x: [T=16, N] fp32, out: spikes [T=16, N] fp32. N = B*C*H*W = 4,194,304.
//
// Latency-hiding structure: issue all 16 timestep loads up front (16
// outstanding global_load_dwordx4 per wave = 16 KiB in flight), then run
// the serial recurrence from registers, streaming nontemporal stores.
//
// Note: __builtin_nontemporal_load/store require a clang ext_vector type,
// not HIP's float4 class.

#ifndef PLIF_T
#define PLIF_T 16
#endif

typedef float f32x4 __attribute__((ext_vector_type(4)));

__global__ __launch_bounds__(256) void plif_fwd_kernel(
    const f32x4* __restrict__ x, f32x4* __restrict__ out, int n4) {
    int i = blockIdx.x * blockDim.x + threadIdx.x;
    if (i >= n4) return;

    // Phase 1: issue all T loads back-to-back (independent addresses).
    // Fully unrolled, compile-time indices -> stays in VGPRs, no scratch.
    f32x4 xt[PLIF_T];
    #pragma unroll
    for (int t = 0; t < PLIF_T; ++t) {
        xt[t] = __builtin_nontemporal_load(&x[(size_t)t * (size_t)n4 + (size_t)i]);
    }

    // Phase 2: serial recurrence from registers; stores stream out.
    f32x4 v = (f32x4)(0.f, 0.f, 0.f, 0.f);
    #pragma unroll
    for (int t = 0; t < PLIF_T; ++t) {
        v += xt[t];

        f32x4 s;
        s.x = (v.x > 1.0f) ? 1.0f : 0.0f;
        s.y = (v.y > 1.0f) ? 1.0f : 0.0f;
        s.z = (v.z > 1.0f) ? 1.0f : 0.0f;
        s.w = (v.w > 1.0f) ? 1.0f : 0.0f;

        v -= s;

        __builtin_nontemporal_store(s, &out[(size_t)t * (size_t)n4 + (size_t)i]);
    }
}

extern "C" void kernel_launch(void* const* d_in, const int* in_sizes, int n_in,
                              void* d_out, int out_size, void* d_ws, size_t ws_size,
                              hipStream_t stream) {
    const float* x = (const float*)d_in[0];
    float* out = (float*)d_out;

    const int total = in_sizes[0];          // T * N
    const int n = total / PLIF_T;           // spatial elements per timestep
    const int n4 = n / 4;                   // float4 groups per timestep

    const int block = 256;
    const int grid = (n4 + block - 1) / block;

    plif_fwd_kernel<<<grid, block, 0, stream>>>(
        (const f32x4*)x, (f32x4*)out, n4);
}